// Round 2
// baseline (966.955 us; speedup 1.0000x reference)
//
#include <hip/hip_runtime.h>
#include <math.h>

// Problem constants: B=64, D=512, H=HID=512 -> M = B*D = 32768, K = 512.
#define MM 32768
#define KK 512
#define BM 128
#define BN 128
#define BK 64           // staged K per barrier pair; computed as 2 halves of 32

typedef float  f32x4  __attribute__((ext_vector_type(4)));
typedef __bf16 bf16x8 __attribute__((ext_vector_type(8)));
typedef unsigned short u16x8 __attribute__((ext_vector_type(8)));

__device__ __forceinline__ unsigned short f2bf(float f) {
    union { float f; unsigned int u; } v; v.f = f;
    unsigned int r = v.u + 0x7fffu + ((v.u >> 16) & 1u);  // RNE
    return (unsigned short)(r >> 16);
}

__device__ __forceinline__ void gl_lds16(const void* g, void* l) {
    __builtin_amdgcn_global_load_lds((const __attribute__((address_space(1))) void*)g,
                                     (__attribute__((address_space(3))) void*)l,
                                     16, 0, 0);
}

// ---------------------------------------------------------------------------
// fsum = fea1+fea2+fea3+fea4, cast to bf16.  8 elements / thread.
// ---------------------------------------------------------------------------
__global__ __launch_bounds__(256)
void fsum_cast(const float* __restrict__ f1, const float* __restrict__ f2,
               const float* __restrict__ f3, const float* __restrict__ f4,
               unsigned short* __restrict__ out)
{
    const long i = ((long)blockIdx.x * 256 + threadIdx.x) * 8;
    f32x4 s0 = *(const f32x4*)(f1 + i);
    f32x4 s1 = *(const f32x4*)(f1 + i + 4);
    s0 += *(const f32x4*)(f2 + i);  s1 += *(const f32x4*)(f2 + i + 4);
    s0 += *(const f32x4*)(f3 + i);  s1 += *(const f32x4*)(f3 + i + 4);
    s0 += *(const f32x4*)(f4 + i);  s1 += *(const f32x4*)(f4 + i + 4);
    u16x8 o;
    o[0] = f2bf(s0[0]); o[1] = f2bf(s0[1]); o[2] = f2bf(s0[2]); o[3] = f2bf(s0[3]);
    o[4] = f2bf(s1[0]); o[5] = f2bf(s1[1]); o[6] = f2bf(s1[2]); o[7] = f2bf(s1[3]);
    *(u16x8*)(out + i) = o;
}

// ---------------------------------------------------------------------------
// Weight prep: transpose to (N,K) row-major bf16.
//   z = 0     : WgT[n][k]    = 0.25 * W_gcn[k][n]        (Ahat==0.25*ones folded)
//   z = 1..4  : W1effT[n][k] = sum_b W1_i[b*512 + k][n]  (z-concat collapse)
//   z = 5..8  : W2T[n][k]    = W2_i[k][n]
// ---------------------------------------------------------------------------
struct WArgs {
    const float* src[9];
    unsigned short* dst[9];
};

__global__ __launch_bounds__(256)
void wprep(WArgs a)
{
    __shared__ float t[32][33];
    const int z  = blockIdx.z;
    const float* __restrict__ src = a.src[z];
    unsigned short* __restrict__ dst = a.dst[z];
    const int k0 = blockIdx.x * 32;
    const int n0 = blockIdx.y * 32;
    const int tx = threadIdx.x;
    for (int kk = threadIdx.y; kk < 32; kk += 8) {
        float v = src[(long)(k0 + kk) * 512 + n0 + tx];
        if (z >= 1 && z <= 4) {
            v += src[(long)(512  + k0 + kk) * 512 + n0 + tx];
            v += src[(long)(1024 + k0 + kk) * 512 + n0 + tx];
            v += src[(long)(1536 + k0 + kk) * 512 + n0 + tx];
        }
        if (z == 0) v *= 0.25f;
        t[kk][tx] = v;
    }
    __syncthreads();
    for (int nn = threadIdx.y; nn < 32; nn += 8) {
        dst[(long)(n0 + nn) * 512 + k0 + tx] = f2bf(t[tx][nn]);
    }
}

// ---------------------------------------------------------------------------
// GEMM: C = A(M x 512 bf16) @ Bt(rows x 512 bf16)^T + bias epilogue.
// MODE 0: N=512;  store bf16(v+bias)              -> s            grid (256,4)
// MODE 1: N=2048; store bf16(relu(v+bias))        -> h[branch]    grid (256,16)
//         branch = n0>>9 (block-uniform); dest col = col&511.
// MODE 2: N=512, blockIdx.z=branch; store fp32 sigmoid(v+bias)*fea grid (256,4,4)
// 128x128 tile, BK=64 (2 sequential 32-halves), 4 waves, 16x16x32 bf16 MFMA.
// ---------------------------------------------------------------------------
struct GArgs {
    const unsigned short* Az[4];   // A per branch (modes 0/1 use Az[0])
    const unsigned short* Bt;      // transposed weights, rows x 512
    const float* bias[4];
    const float* fea[4];
    void* out;
};

template<int MODE>
__global__ __launch_bounds__(256)
void gemm_ep(GArgs a)
{
    __shared__ unsigned short As[BM * BK];   // 16 KB
    __shared__ unsigned short Bs[BN * BK];   // 16 KB

    const int tid  = threadIdx.x;
    const int lane = tid & 63;
    const int wave = tid >> 6;
    const int m0 = blockIdx.x * BM;
    const int n0 = blockIdx.y * BN;
    const int zz = (MODE == 2) ? blockIdx.z : ((MODE == 1) ? (n0 >> 9) : 0);

    const unsigned short* A  = a.Az[(MODE == 2) ? zz : 0];
    const unsigned short* Bt = (MODE == 2) ? (a.Bt + (size_t)zz * 512 * 512) : a.Bt;

    // staging role (wave-uniform): waves 0/1 stage A rows 0-63/64-127, 2/3 Bt.
    const bool isA = (wave < 2);
    const int rowbase = (wave & 1) * 64;
    const unsigned short* gsrc = isA ? A : Bt;
    unsigned short* ldst = isA ? As : Bs;
    const int r8 = lane >> 3;    // 0..7 row within 8-row chunk
    const int s8 = lane & 7;     // 16B segment within 128B row
    const long grow0 = (isA ? (long)m0 : (long)n0) + rowbase;
    const unsigned short* gbase0 = gsrc + (grow0 + r8) * KK + s8 * 8;
    unsigned short* lbase = ldst + rowbase * BK;

    // fragment geometry: A[m=lane&15][k=(lane>>4)*8+j], B mirrored.
    const int frow = lane & 15;
    const int fk   = (lane >> 4) * 8;
    const int wrow = wave >> 1;
    const int wcol = wave & 1;

    f32x4 acc[4][4] = {};

    for (int ks = 0; ks < KK / BK; ++ks) {                 // 8 iterations
        const unsigned short* gb = gbase0 + ks * BK;
        #pragma unroll
        for (int c = 0; c < 8; ++c) {                      // 64 rows / wave
            gl_lds16(gb + (long)(c * 8) * KK, lbase + c * 8 * BK);
        }
        __syncthreads();   // drains vmcnt for the async LDS loads

        #pragma unroll
        for (int hh = 0; hh < 2; ++hh) {                   // two 32-wide K halves
            bf16x8 afr[4], bfr[4];
            #pragma unroll
            for (int i = 0; i < 4; ++i)
                afr[i] = *(const bf16x8*)(As + (wrow * 64 + i * 16 + frow) * BK
                                             + hh * 32 + fk);
            #pragma unroll
            for (int j = 0; j < 4; ++j)
                bfr[j] = *(const bf16x8*)(Bs + (wcol * 64 + j * 16 + frow) * BK
                                             + hh * 32 + fk);
            #pragma unroll
            for (int i = 0; i < 4; ++i)
                #pragma unroll
                for (int j = 0; j < 4; ++j)
                    acc[i][j] = __builtin_amdgcn_mfma_f32_16x16x32_bf16(
                        afr[i], bfr[j], acc[i][j], 0, 0, 0);
        }
        __syncthreads();   // protect LDS from next iteration's staging
    }

    // epilogue: C/D layout col=lane&15, row=(lane>>4)*4+reg  [m89-verified]
    const int cq = (lane >> 4) * 4;
    const int cc = lane & 15;
    const float* bias_p = a.bias[zz];
    #pragma unroll
    for (int j = 0; j < 4; ++j) {
        const int col = n0 + wcol * 64 + j * 16 + cc;
        const int coll = col & 511;
        const float bv = bias_p[coll];
        #pragma unroll
        for (int i = 0; i < 4; ++i) {
            #pragma unroll
            for (int rr = 0; rr < 4; ++rr) {
                const int row = m0 + wrow * 64 + i * 16 + cq + rr;
                float v = acc[i][j][rr] + bv;
                if (MODE == 0) {
                    ((unsigned short*)a.out)[(long)row * 512 + col] = f2bf(v);
                } else if (MODE == 1) {
                    ((unsigned short*)a.out)[((long)zz * MM + row) * 512 + coll]
                        = f2bf(fmaxf(v, 0.0f));
                } else {
                    const float g = 1.0f / (1.0f + __expf(-v));
                    ((float*)a.out)[((long)zz * MM + row) * 512 + col]
                        = g * a.fea[zz][(long)row * 512 + col];
                }
            }
        }
    }
}

// ---------------------------------------------------------------------------
extern "C" void kernel_launch(void* const* d_in, const int* in_sizes, int n_in,
                              void* d_out, int out_size, void* d_ws, size_t ws_size,
                              hipStream_t stream)
{
    (void)in_sizes; (void)n_in; (void)out_size; (void)ws_size;

    const float* fea[4] = {(const float*)d_in[0], (const float*)d_in[1],
                           (const float*)d_in[2], (const float*)d_in[3]};
    const float* W_gcn = (const float*)d_in[4];
    const float* b_gcn = (const float*)d_in[5];
    const float *W1[4], *b1[4], *W2[4], *b2[4];
    for (int i = 0; i < 4; ++i) {
        W1[i] = (const float*)d_in[6 + 4 * i];
        b1[i] = (const float*)d_in[7 + 4 * i];
        W2[i] = (const float*)d_in[8 + 4 * i];
        b2[i] = (const float*)d_in[9 + 4 * i];
    }

    // workspace (bytes): [0,32M) fsum bf16; [32M,64M) s bf16;
    // [64M,192M) h bf16 4 branches x (M x 512); [192M,196.5M) 9 bf16 weights.
    char* ws = (char*)d_ws;
    unsigned short* fsum_b = (unsigned short*)ws;
    unsigned short* s_buf  = (unsigned short*)(ws + (size_t)33554432);
    unsigned short* h_buf  = (unsigned short*)(ws + (size_t)67108864);
    unsigned short* wbuf   = (unsigned short*)(ws + (size_t)201326592);
    unsigned short* WgT     = wbuf;                                  // 512x512
    unsigned short* W1T_all = wbuf + (size_t)262144;                 // 2048x512
    unsigned short* W2T_all = wbuf + (size_t)5 * 262144;             // 4x 512x512

    fsum_cast<<<8192, 256, 0, stream>>>(fea[0], fea[1], fea[2], fea[3], fsum_b);

    WArgs wa;
    wa.src[0] = W_gcn; wa.dst[0] = WgT;
    for (int i = 0; i < 4; ++i) {
        wa.src[1 + i] = W1[i]; wa.dst[1 + i] = W1T_all + (size_t)i * 262144;
        wa.src[5 + i] = W2[i]; wa.dst[5 + i] = W2T_all + (size_t)i * 262144;
    }
    wprep<<<dim3(16, 16, 9), dim3(32, 8), 0, stream>>>(wa);

    // s = fsum @ WgT^T + b_gcn
    GArgs g0 = {};
    g0.Az[0] = fsum_b; g0.Bt = WgT; g0.bias[0] = b_gcn; g0.out = s_buf;
    gemm_ep<0><<<dim3(MM / BM, 4), 256, 0, stream>>>(g0);

    // h[br] = relu(s @ W1eff[br]^T + b1[br])  -- one N=2048 GEMM
    GArgs g1 = {};
    g1.Az[0] = s_buf; g1.Bt = W1T_all;
    for (int i = 0; i < 4; ++i) g1.bias[i] = b1[i];
    g1.out = h_buf;
    gemm_ep<1><<<dim3(MM / BM, 16), 256, 0, stream>>>(g1);

    // out[br] = sigmoid(h[br] @ W2[br]^T + b2[br]) * fea[br]
    GArgs g2 = {};
    for (int i = 0; i < 4; ++i) {
        g2.Az[i]   = h_buf + (size_t)i * MM * 512;
        g2.bias[i] = b2[i];
        g2.fea[i]  = fea[i];
    }
    g2.Bt = W2T_all; g2.out = d_out;
    gemm_ep<2><<<dim3(MM / BM, 4, 4), 256, 0, stream>>>(g2);
}